// Round 3
// baseline (2323.847 us; speedup 1.0000x reference)
//
#include <hip/hip_runtime.h>
#include <math.h>

#define BB 256
#define TT 2048
#define HH 64

typedef _Float16 half2v __attribute__((ext_vector_type(2)));
typedef __fp16  fp16v2 __attribute__((ext_vector_type(2)));
union H2I { half2v h; int i; };

__device__ __forceinline__ float tanh_fast(float v) {
    // tanh(x) = 1 - 2/(e^{2x}+1); saturates correctly at +/-inf
    float e = __expf(2.0f * v);
    return 1.0f - 2.0f / (e + 1.0f);
}

#if __has_builtin(__builtin_amdgcn_fdot2)
__device__ __forceinline__ float fdot2(half2v a, half2v b, float c) {
    return __builtin_amdgcn_fdot2(a, b, c, false);
}
#else
__device__ __forceinline__ float fdot2(half2v a, half2v b, float c) {
    return c + (float)a.x * (float)b.x + (float)a.y * (float)b.y;
}
#endif

__device__ __forceinline__ half2v pack_pair(float a, float b) {
#if __has_builtin(__builtin_amdgcn_cvt_pkrtz)
    fp16v2 r = __builtin_amdgcn_cvt_pkrtz(a, b);
    return __builtin_bit_cast(half2v, r);
#else
    half2v r; r.x = (_Float16)a; r.y = (_Float16)b; return r;
#endif
}

// broadcast a packed f16x2 from a (compile-time-uniform) lane to all lanes
__device__ __forceinline__ half2v bcast_pair(half2v v, int lane) {
    H2I u; u.h = v;
    H2I w; w.i = __builtin_amdgcn_readlane(u.i, lane);
    return w.h;
}

__global__ __launch_bounds__(64, 1)
void pgjanet_kernel(const float* __restrict__ x,
                    const float* __restrict__ h0,
                    const float* __restrict__ Wa,  const float* __restrict__ ba,
                    const float* __restrict__ Wp1, const float* __restrict__ bp1,
                    const float* __restrict__ Wp2, const float* __restrict__ bp2,
                    const float* __restrict__ Wf,  const float* __restrict__ bf,
                    const float* __restrict__ Wg,  const float* __restrict__ bg,
                    const float* __restrict__ Wo,  const float* __restrict__ bo,
                    float* __restrict__ out)
{
    const int b = blockIdx.x;
    const int j = threadIdx.x;   // hidden index == lane, one wave per row

    // ---- preload + f16-pack weights into VGPRs (row j of each matrix) ----
    half2v wa[32], wp1[32], wp2[32], wfh[32], wfu[32], wgh[32], wgu[32];
#pragma unroll
    for (int m = 0; m < 32; ++m) {
        wa[m]  = pack_pair(Wa [j * (HH + 1) + 2 * m], Wa [j * (HH + 1) + 2 * m + 1]);
        wp1[m] = pack_pair(Wp1[j * (HH + 1) + 2 * m], Wp1[j * (HH + 1) + 2 * m + 1]);
        wp2[m] = pack_pair(Wp2[j * (HH + 1) + 2 * m], Wp2[j * (HH + 1) + 2 * m + 1]);
        wfh[m] = pack_pair(Wf [j * (2 * HH) + 2 * m], Wf [j * (2 * HH) + 2 * m + 1]);
        wfu[m] = pack_pair(Wf [j * (2 * HH) + HH + 2 * m], Wf [j * (2 * HH) + HH + 2 * m + 1]);
        wgh[m] = pack_pair(Wg [j * (2 * HH) + 2 * m], Wg [j * (2 * HH) + 2 * m + 1]);
        wgu[m] = pack_pair(Wg [j * (2 * HH) + HH + 2 * m], Wg [j * (2 * HH) + HH + 2 * m + 1]);
    }
    const float waH  = Wa [j * (HH + 1) + HH];   // extra-column weights (fp32)
    const float wp1H = Wp1[j * (HH + 1) + HH];
    const float wp2H = Wp2[j * (HH + 1) + HH];
    const float ba_r = ba[j], bp1_r = bp1[j], bp2_r = bp2[j];
    const float bf_r = bf[j], bg_r = bg[j];
    const float wo0 = Wo[j], wo1 = Wo[HH + j];
    const float bo0 = bo[0], bo1 = bo[1];

    float h = h0[b * HH + j];

    const float* xp = x   + (size_t)b * (TT * 2);
    float*       yp = out + (size_t)b * (TT * 2);

    float xi = xp[0], xq = xp[1];   // software-pipelined x load

    for (int t = 0; t < TT; ++t) {
        const int tn = (t + 1 < TT) ? (t + 1) : (TT - 1);
        float xi_n = xp[2 * tn];
        float xq_n = xp[2 * tn + 1];

        // pack h into f16 pairs and broadcast all 32 pairs to wave-uniform regs
        float hnbr = __shfl_down(h, 1, 64);
        half2v hp = pack_pair(h, hnbr);
        half2v sh[32];
#pragma unroll
        for (int m = 0; m < 32; ++m) sh[m] = bcast_pair(hp, 2 * m);

        // phase 1: a, p1, p2 pre-activations (h part), 2 accumulators each
        float aa0 = 0.f, aa1 = 0.f, pb0 = 0.f, pb1 = 0.f, pc0 = 0.f, pc1 = 0.f;
#pragma unroll
        for (int m = 0; m < 16; ++m) {
            aa0 = fdot2(sh[m],      wa[m],       aa0);
            aa1 = fdot2(sh[m + 16], wa[m + 16],  aa1);
            pb0 = fdot2(sh[m],      wp1[m],      pb0);
            pb1 = fdot2(sh[m + 16], wp1[m + 16], pb1);
            pc0 = fdot2(sh[m],      wp2[m],      pc0);
            pc1 = fdot2(sh[m + 16], wp2[m + 16], pc1);
        }

        // x-derived scalars (fp32)
        float amp = sqrtf(xi * xi + xq * xq);
        float inv = (amp > 0.f) ? (1.0f / amp) : 0.0f;
        float ct  = (amp > 0.f) ? (xi * inv) : 1.0f;   // cos(atan2(q,i)); atan2(0,0)=0
        float st  = xq * inv;                          // sin(atan2(q,i))

        float a  = tanh_fast(aa0 + aa1 + fmaf(amp, waH,  ba_r));
        float p1 = tanh_fast(pb0 + pb1 + fmaf(ct,  wp1H, bp1_r));
        float p2 = tanh_fast(pc0 + pc1 + fmaf(st,  wp2H, bp2_r));
        float u  = a * p1 * p2 * (1.f - a) * (1.f - p1) * (1.f - p2);

        // pack + broadcast u pairs
        float unbr = __shfl_down(u, 1, 64);
        half2v up = pack_pair(u, unbr);
        half2v su[32];
#pragma unroll
        for (int m = 0; m < 32; ++m) su[m] = bcast_pair(up, 2 * m);

        // phase 2: f, g over concat [h, u]
        float f0 = 0.f, f1 = 0.f, g0 = 0.f, g1 = 0.f;
#pragma unroll
        for (int m = 0; m < 32; ++m) {
            f0 = fdot2(sh[m], wfh[m], f0);
            f1 = fdot2(su[m], wfu[m], f1);
            g0 = fdot2(sh[m], wgh[m], g0);
            g1 = fdot2(su[m], wgu[m], g1);
        }
        float f = 1.0f / (1.0f + __expf(-(f0 + f1 + bf_r)));
        float g = tanh_fast(g0 + g1 + bg_r);
        h = fmaf(f, h - g, g);   // f*h + (1-f)*g

        // y_t = h @ Wo.T + bo — in-wave reduce; overlaps next step's dot stream
        float y0 = h * wo0;
        float y1 = h * wo1;
#pragma unroll
        for (int m = 32; m >= 1; m >>= 1) {
            y0 += __shfl_xor(y0, m, 64);
            y1 += __shfl_xor(y1, m, 64);
        }
        if (j == 0) {
            yp[2 * t]     = y0 + bo0;
            yp[2 * t + 1] = y1 + bo1;
        }

        xi = xi_n; xq = xq_n;
    }
}

extern "C" void kernel_launch(void* const* d_in, const int* in_sizes, int n_in,
                              void* d_out, int out_size, void* d_ws, size_t ws_size,
                              hipStream_t stream) {
    const float* x   = (const float*)d_in[0];
    const float* h0  = (const float*)d_in[1];
    const float* Wa  = (const float*)d_in[2];
    const float* ba  = (const float*)d_in[3];
    const float* Wp1 = (const float*)d_in[4];
    const float* bp1 = (const float*)d_in[5];
    const float* Wp2 = (const float*)d_in[6];
    const float* bp2 = (const float*)d_in[7];
    const float* Wf  = (const float*)d_in[8];
    const float* bf  = (const float*)d_in[9];
    const float* Wg  = (const float*)d_in[10];
    const float* bg  = (const float*)d_in[11];
    const float* Wo  = (const float*)d_in[12];
    const float* bo  = (const float*)d_in[13];
    float* out = (float*)d_out;

    pgjanet_kernel<<<dim3(BB), dim3(64), 0, stream>>>(
        x, h0, Wa, ba, Wp1, bp1, Wp2, bp2, Wf, bf, Wg, bg, Wo, bo, out);
}

// Round 5
// 2052.695 us; speedup vs baseline: 1.1321x; 1.1321x over previous
//
#include <hip/hip_runtime.h>
#include <math.h>

#define BB 256
#define TT 2048
#define HH 64

typedef _Float16 half2v __attribute__((ext_vector_type(2)));
typedef __fp16  fp16v2 __attribute__((ext_vector_type(2)));
union H2I { half2v h; int i; };

__device__ __forceinline__ float tanh_fast(float v) {
    // tanh(x) = 1 - 2/(e^{2x}+1); saturates correctly at +/-inf
    float e = __expf(2.0f * v);
    return 1.0f - 2.0f / (e + 1.0f);
}

__device__ __forceinline__ float fdot2(half2v a, half2v b, float c) {
    return __builtin_amdgcn_fdot2(a, b, c, false);
}

__device__ __forceinline__ half2v pack_pair(float a, float b) {
    fp16v2 r = __builtin_amdgcn_cvt_pkrtz(a, b);
    return __builtin_bit_cast(half2v, r);
}

// broadcast a packed f16x2 from a (compile-time-uniform) lane to all lanes
__device__ __forceinline__ half2v bcast_pair(half2v v, int lane) {
    H2I u; u.h = v;
    H2I w; w.i = __builtin_amdgcn_readlane(u.i, lane);
    return w.h;
}

// neighbor value within a quad: lane j gets lane j^1 (DPP quad_perm [1,0,3,2])
__device__ __forceinline__ float dpp_neighbor(float v) {
    return __int_as_float(__builtin_amdgcn_mov_dpp(__float_as_int(v), 0xB1, 0xf, 0xf, true));
}

template <int CTRL>
__device__ __forceinline__ float dpp_add_stage(float v) {
    int t = __builtin_amdgcn_update_dpp(0, __float_as_int(v), CTRL, 0xf, 0xf, true);
    return v + __int_as_float(t);
}

// full 64-lane sum, result valid in lane 63; all-VALU (no LDS pipe)
__device__ __forceinline__ float wave_sum_dpp(float v) {
    v = dpp_add_stage<0x111>(v);  // row_shr:1
    v = dpp_add_stage<0x112>(v);  // row_shr:2
    v = dpp_add_stage<0x114>(v);  // row_shr:4
    v = dpp_add_stage<0x118>(v);  // row_shr:8   -> lane15 of each row16 = row sum
    v = dpp_add_stage<0x142>(v);  // row_bcast15 -> lane31 = rows0+1, lane63 = rows2+3
    v = dpp_add_stage<0x143>(v);  // row_bcast31 -> lane63 = total
    return v;
}

__global__ __launch_bounds__(64, 1)
void pgjanet_kernel(const float* __restrict__ x,
                    const float* __restrict__ h0,
                    const float* __restrict__ Wa,  const float* __restrict__ ba,
                    const float* __restrict__ Wp1, const float* __restrict__ bp1,
                    const float* __restrict__ Wp2, const float* __restrict__ bp2,
                    const float* __restrict__ Wf,  const float* __restrict__ bf,
                    const float* __restrict__ Wg,  const float* __restrict__ bg,
                    const float* __restrict__ Wo,  const float* __restrict__ bo,
                    float* __restrict__ out)
{
    const int b = blockIdx.x;
    const int j = threadIdx.x;   // hidden index == lane, one wave per row

    // ---- preload + f16-pack weights into VGPRs (row j of each matrix) ----
    half2v wa[32], wp1[32], wp2[32], wfh[32], wfu[32], wgh[32], wgu[32];
#pragma unroll
    for (int m = 0; m < 32; ++m) {
        wa[m]  = pack_pair(Wa [j * (HH + 1) + 2 * m], Wa [j * (HH + 1) + 2 * m + 1]);
        wp1[m] = pack_pair(Wp1[j * (HH + 1) + 2 * m], Wp1[j * (HH + 1) + 2 * m + 1]);
        wp2[m] = pack_pair(Wp2[j * (HH + 1) + 2 * m], Wp2[j * (HH + 1) + 2 * m + 1]);
        wfh[m] = pack_pair(Wf [j * (2 * HH) + 2 * m], Wf [j * (2 * HH) + 2 * m + 1]);
        wfu[m] = pack_pair(Wf [j * (2 * HH) + HH + 2 * m], Wf [j * (2 * HH) + HH + 2 * m + 1]);
        wgh[m] = pack_pair(Wg [j * (2 * HH) + 2 * m], Wg [j * (2 * HH) + 2 * m + 1]);
        wgu[m] = pack_pair(Wg [j * (2 * HH) + HH + 2 * m], Wg [j * (2 * HH) + HH + 2 * m + 1]);
    }
    const float waH  = Wa [j * (HH + 1) + HH];   // extra-column weights (fp32)
    const float wp1H = Wp1[j * (HH + 1) + HH];
    const float wp2H = Wp2[j * (HH + 1) + HH];
    const float ba_r = ba[j], bp1_r = bp1[j], bp2_r = bp2[j];
    const float bf_r = bf[j], bg_r = bg[j];
    const float wo0 = Wo[j], wo1 = Wo[HH + j];
    const float bo0 = bo[0], bo1 = bo[1];

    float h = h0[b * HH + j];

    const float* xp = x   + (size_t)b * (TT * 2);
    float*       yp = out + (size_t)b * (TT * 2);

    float xi = xp[0], xq = xp[1];   // software-pipelined x load

    for (int t = 0; t < TT; ++t) {
        const int tn = (t + 1 < TT) ? (t + 1) : (TT - 1);
        float xi_n = xp[2 * tn];
        float xq_n = xp[2 * tn + 1];

        // pack h pairs: even lane 2m holds (h_2m, h_2m+1); broadcast 32 pairs
        float hnbr = dpp_neighbor(h);
        half2v hp = pack_pair(h, hnbr);
        half2v sh[32];
#pragma unroll
        for (int m = 0; m < 32; ++m) sh[m] = bcast_pair(hp, 2 * m);

        // ---- phase A: everything that depends only on h ----
        // 20 independent chains of 8 dot2 (a, p1, p2, f_h, g_h)
        float va[4], vp1[4], vp2[4], vf[4], vg[4];
#pragma unroll
        for (int c = 0; c < 4; ++c) { va[c] = 0.f; vp1[c] = 0.f; vp2[c] = 0.f; vf[c] = 0.f; vg[c] = 0.f; }
#pragma unroll
        for (int c = 0; c < 4; ++c) {
#pragma unroll
            for (int m = 0; m < 8; ++m) {
                const int i = 8 * c + m;
                va[c]  = fdot2(sh[i], wa[i],  va[c]);
                vp1[c] = fdot2(sh[i], wp1[i], vp1[c]);
                vp2[c] = fdot2(sh[i], wp2[i], vp2[c]);
                vf[c]  = fdot2(sh[i], wfh[i], vf[c]);
                vg[c]  = fdot2(sh[i], wgh[i], vg[c]);
            }
        }

        // x-derived scalars (fp32)
        float amp = sqrtf(xi * xi + xq * xq);
        float inv = (amp > 0.f) ? (1.0f / amp) : 0.0f;
        float ct  = (amp > 0.f) ? (xi * inv) : 1.0f;   // cos(atan2(q,i)); atan2(0,0)=0
        float st  = xq * inv;                          // sin(atan2(q,i))

        float pre_a = (va[0] + va[1]) + (va[2] + va[3]) + fmaf(amp, waH,  ba_r);
        float pre_1 = (vp1[0] + vp1[1]) + (vp1[2] + vp1[3]) + fmaf(ct, wp1H, bp1_r);
        float pre_2 = (vp2[0] + vp2[1]) + (vp2[2] + vp2[3]) + fmaf(st, wp2H, bp2_r);
        float a  = tanh_fast(pre_a);
        float p1 = tanh_fast(pre_1);
        float p2 = tanh_fast(pre_2);
        float u  = (a * (1.f - a)) * (p1 * (1.f - p1)) * (p2 * (1.f - p2));

        // pack + broadcast u pairs
        float unbr = dpp_neighbor(u);
        half2v up = pack_pair(u, unbr);
        half2v su[32];
#pragma unroll
        for (int m = 0; m < 32; ++m) su[m] = bcast_pair(up, 2 * m);

        // ---- phase C: u-part of f, g — 8 independent chains of 8 ----
        float uf[4], ug[4];
#pragma unroll
        for (int c = 0; c < 4; ++c) { uf[c] = 0.f; ug[c] = 0.f; }
#pragma unroll
        for (int c = 0; c < 4; ++c) {
#pragma unroll
            for (int m = 0; m < 8; ++m) {
                const int i = 8 * c + m;
                uf[c] = fdot2(su[i], wfu[i], uf[c]);
                ug[c] = fdot2(su[i], wgu[i], ug[c]);
            }
        }

        float pre_f = ((vf[0] + vf[1]) + (vf[2] + vf[3])) + ((uf[0] + uf[1]) + (uf[2] + uf[3])) + bf_r;
        float pre_g = ((vg[0] + vg[1]) + (vg[2] + vg[3])) + ((ug[0] + ug[1]) + (ug[2] + ug[3])) + bg_r;
        float f = 1.0f / (1.0f + __expf(-pre_f));
        float g = tanh_fast(pre_g);
        h = fmaf(f, h - g, g);   // f*h + (1-f)*g

        // y_t = h @ Wo.T + bo — all-VALU DPP reduce (no LDS pipe)
        float y0 = wave_sum_dpp(h * wo0);
        float y1 = wave_sum_dpp(h * wo1);
        if (j == 63) {
            yp[2 * t]     = y0 + bo0;
            yp[2 * t + 1] = y1 + bo1;
        }

        xi = xi_n; xq = xq_n;
    }
}

extern "C" void kernel_launch(void* const* d_in, const int* in_sizes, int n_in,
                              void* d_out, int out_size, void* d_ws, size_t ws_size,
                              hipStream_t stream) {
    const float* x   = (const float*)d_in[0];
    const float* h0  = (const float*)d_in[1];
    const float* Wa  = (const float*)d_in[2];
    const float* ba  = (const float*)d_in[3];
    const float* Wp1 = (const float*)d_in[4];
    const float* bp1 = (const float*)d_in[5];
    const float* Wp2 = (const float*)d_in[6];
    const float* bp2 = (const float*)d_in[7];
    const float* Wf  = (const float*)d_in[8];
    const float* bf  = (const float*)d_in[9];
    const float* Wg  = (const float*)d_in[10];
    const float* bg  = (const float*)d_in[11];
    const float* Wo  = (const float*)d_in[12];
    const float* bo  = (const float*)d_in[13];
    float* out = (float*)d_out;

    pgjanet_kernel<<<dim3(BB), dim3(64), 0, stream>>>(
        x, h0, Wa, ba, Wp1, bp1, Wp2, bp2, Wf, bf, Wg, bg, Wo, bo, out);
}

// Round 6
// 1959.296 us; speedup vs baseline: 1.1861x; 1.0477x over previous
//
#include <hip/hip_runtime.h>
#include <math.h>

#define BB 256
#define TT 2048
#define HH 64

typedef _Float16 half2v __attribute__((ext_vector_type(2)));
typedef __fp16  fp16v2 __attribute__((ext_vector_type(2)));
union H2I { half2v h; int i; };

__device__ __forceinline__ float tanh_fast(float v) {
    // tanh(x) = 1 - 2/(e^{2x}+1); saturates correctly at +/-inf
    float e = __expf(2.0f * v);
    return 1.0f - 2.0f / (e + 1.0f);
}

__device__ __forceinline__ float fdot2(half2v a, half2v b, float c) {
    return __builtin_amdgcn_fdot2(a, b, c, false);
}

__device__ __forceinline__ half2v pack_pair(float a, float b) {
    fp16v2 r = __builtin_amdgcn_cvt_pkrtz(a, b);
    return __builtin_bit_cast(half2v, r);
}

// force a value to live in a VGPR across the loop (defeat load-rematerialization)
__device__ __forceinline__ void pin_h2(half2v& v) {
    H2I u; u.h = v;
    asm volatile("" : "+v"(u.i));
    v = u.h;
}

// broadcast a packed f16x2 from a (compile-time-uniform) lane to all lanes
__device__ __forceinline__ half2v bcast_pair(half2v v, int lane) {
    H2I u; u.h = v;
    H2I w; w.i = __builtin_amdgcn_readlane(u.i, lane);
    return w.h;
}

// neighbor value within a quad: lane j gets lane j^1 (DPP quad_perm [1,0,3,2])
__device__ __forceinline__ float dpp_neighbor(float v) {
    return __int_as_float(__builtin_amdgcn_mov_dpp(__float_as_int(v), 0xB1, 0xf, 0xf, true));
}

template <int CTRL>
__device__ __forceinline__ float dpp_add_stage(float v) {
    int t = __builtin_amdgcn_update_dpp(0, __float_as_int(v), CTRL, 0xf, 0xf, true);
    return v + __int_as_float(t);
}

// full 64-lane sum, result valid in lane 63; all-VALU (no LDS pipe)
__device__ __forceinline__ float wave_sum_dpp(float v) {
    v = dpp_add_stage<0x111>(v);  // row_shr:1
    v = dpp_add_stage<0x112>(v);  // row_shr:2
    v = dpp_add_stage<0x114>(v);  // row_shr:4
    v = dpp_add_stage<0x118>(v);  // row_shr:8   -> lane15 of each row16 = row sum
    v = dpp_add_stage<0x142>(v);  // row_bcast15 -> lane31 = rows0+1, lane63 = rows2+3
    v = dpp_add_stage<0x143>(v);  // row_bcast31 -> lane63 = total
    return v;
}

__global__ __launch_bounds__(64, 1)
void pgjanet_kernel(const float* __restrict__ x,
                    const float* __restrict__ h0,
                    const float* __restrict__ Wa,  const float* __restrict__ ba,
                    const float* __restrict__ Wp1, const float* __restrict__ bp1,
                    const float* __restrict__ Wp2, const float* __restrict__ bp2,
                    const float* __restrict__ Wf,  const float* __restrict__ bf,
                    const float* __restrict__ Wg,  const float* __restrict__ bg,
                    const float* __restrict__ Wo,  const float* __restrict__ bo,
                    float* __restrict__ out)
{
    const int b = blockIdx.x;
    const int j = threadIdx.x;   // hidden index == lane, one wave per row

    // ---- stage this row's x sequence in LDS (removes global loads from loop) ----
    __shared__ float xs[TT * 2];   // 16 KB
    {
        const float* xp = x + (size_t)b * (TT * 2);
#pragma unroll 4
        for (int i = j; i < TT * 2; i += 64) xs[i] = xp[i];
    }

    // ---- preload + f16-pack weights into VGPRs (row j of each matrix) ----
    half2v wa[32], wp1[32], wp2[32], wfh[32], wfu[32], wgh[32], wgu[32];
#pragma unroll
    for (int m = 0; m < 32; ++m) {
        wa[m]  = pack_pair(Wa [j * (HH + 1) + 2 * m], Wa [j * (HH + 1) + 2 * m + 1]);
        wp1[m] = pack_pair(Wp1[j * (HH + 1) + 2 * m], Wp1[j * (HH + 1) + 2 * m + 1]);
        wp2[m] = pack_pair(Wp2[j * (HH + 1) + 2 * m], Wp2[j * (HH + 1) + 2 * m + 1]);
        wfh[m] = pack_pair(Wf [j * (2 * HH) + 2 * m], Wf [j * (2 * HH) + 2 * m + 1]);
        wfu[m] = pack_pair(Wf [j * (2 * HH) + HH + 2 * m], Wf [j * (2 * HH) + HH + 2 * m + 1]);
        wgh[m] = pack_pair(Wg [j * (2 * HH) + 2 * m], Wg [j * (2 * HH) + 2 * m + 1]);
        wgu[m] = pack_pair(Wg [j * (2 * HH) + HH + 2 * m], Wg [j * (2 * HH) + HH + 2 * m + 1]);
    }
    // pin every weight value into a VGPR so the allocator cannot re-load in-loop
#pragma unroll
    for (int m = 0; m < 32; ++m) {
        pin_h2(wa[m]);  pin_h2(wp1[m]); pin_h2(wp2[m]);
        pin_h2(wfh[m]); pin_h2(wfu[m]); pin_h2(wgh[m]); pin_h2(wgu[m]);
    }

    const float waH  = Wa [j * (HH + 1) + HH];   // extra-column weights (fp32)
    const float wp1H = Wp1[j * (HH + 1) + HH];
    const float wp2H = Wp2[j * (HH + 1) + HH];
    const float ba_r = ba[j], bp1_r = bp1[j], bp2_r = bp2[j];
    const float bf_r = bf[j], bg_r = bg[j];
    const float wo0 = Wo[j], wo1 = Wo[HH + j];
    const float bo0 = bo[0], bo1 = bo[1];

    float h = h0[b * HH + j];

    float* yp = out + (size_t)b * (TT * 2);

    __syncthreads();   // xs ready (single wave, but keep it correct)
    float xi = xs[0], xq = xs[1];

    for (int t = 0; t < TT; ++t) {
        const int tn = (t + 1 < TT) ? (t + 1) : (TT - 1);
        float xi_n = xs[2 * tn];       // uniform-address LDS read, issued a step early
        float xq_n = xs[2 * tn + 1];

        // pack h pairs: even lane 2m holds (h_2m, h_2m+1); broadcast 32 pairs
        float hnbr = dpp_neighbor(h);
        half2v hp = pack_pair(h, hnbr);
        half2v sh[32];
#pragma unroll
        for (int m = 0; m < 32; ++m) sh[m] = bcast_pair(hp, 2 * m);

        // ---- phase A: everything that depends only on h ----
        // 20 independent chains of 8 dot2 (a, p1, p2, f_h, g_h)
        float va[4], vp1[4], vp2[4], vf[4], vg[4];
#pragma unroll
        for (int c = 0; c < 4; ++c) { va[c] = 0.f; vp1[c] = 0.f; vp2[c] = 0.f; vf[c] = 0.f; vg[c] = 0.f; }
#pragma unroll
        for (int c = 0; c < 4; ++c) {
#pragma unroll
            for (int m = 0; m < 8; ++m) {
                const int i = 8 * c + m;
                va[c]  = fdot2(sh[i], wa[i],  va[c]);
                vp1[c] = fdot2(sh[i], wp1[i], vp1[c]);
                vp2[c] = fdot2(sh[i], wp2[i], vp2[c]);
                vf[c]  = fdot2(sh[i], wfh[i], vf[c]);
                vg[c]  = fdot2(sh[i], wgh[i], vg[c]);
            }
        }

        // x-derived scalars (fp32)
        float amp = sqrtf(xi * xi + xq * xq);
        float inv = (amp > 0.f) ? (1.0f / amp) : 0.0f;
        float ct  = (amp > 0.f) ? (xi * inv) : 1.0f;   // cos(atan2(q,i)); atan2(0,0)=0
        float st  = xq * inv;                          // sin(atan2(q,i))

        float pre_a = (va[0] + va[1]) + (va[2] + va[3]) + fmaf(amp, waH,  ba_r);
        float pre_1 = (vp1[0] + vp1[1]) + (vp1[2] + vp1[3]) + fmaf(ct, wp1H, bp1_r);
        float pre_2 = (vp2[0] + vp2[1]) + (vp2[2] + vp2[3]) + fmaf(st, wp2H, bp2_r);
        float a  = tanh_fast(pre_a);
        float p1 = tanh_fast(pre_1);
        float p2 = tanh_fast(pre_2);
        float u  = (a * (1.f - a)) * (p1 * (1.f - p1)) * (p2 * (1.f - p2));

        // pack + broadcast u pairs
        float unbr = dpp_neighbor(u);
        half2v up = pack_pair(u, unbr);
        half2v su[32];
#pragma unroll
        for (int m = 0; m < 32; ++m) su[m] = bcast_pair(up, 2 * m);

        // ---- phase C: u-part of f, g — 8 independent chains of 8 ----
        float uf[4], ug[4];
#pragma unroll
        for (int c = 0; c < 4; ++c) { uf[c] = 0.f; ug[c] = 0.f; }
#pragma unroll
        for (int c = 0; c < 4; ++c) {
#pragma unroll
            for (int m = 0; m < 8; ++m) {
                const int i = 8 * c + m;
                uf[c] = fdot2(su[i], wfu[i], uf[c]);
                ug[c] = fdot2(su[i], wgu[i], ug[c]);
            }
        }

        float pre_f = ((vf[0] + vf[1]) + (vf[2] + vf[3])) + ((uf[0] + uf[1]) + (uf[2] + uf[3])) + bf_r;
        float pre_g = ((vg[0] + vg[1]) + (vg[2] + vg[3])) + ((ug[0] + ug[1]) + (ug[2] + ug[3])) + bg_r;
        float f = 1.0f / (1.0f + __expf(-pre_f));
        float g = tanh_fast(pre_g);
        h = fmaf(f, h - g, g);   // f*h + (1-f)*g

        // y_t = h @ Wo.T + bo — all-VALU DPP reduce (no LDS pipe)
        float y0 = wave_sum_dpp(h * wo0);
        float y1 = wave_sum_dpp(h * wo1);
        if (j == 63) {
            yp[2 * t]     = y0 + bo0;
            yp[2 * t + 1] = y1 + bo1;
        }

        xi = xi_n; xq = xq_n;
    }
}

extern "C" void kernel_launch(void* const* d_in, const int* in_sizes, int n_in,
                              void* d_out, int out_size, void* d_ws, size_t ws_size,
                              hipStream_t stream) {
    const float* x   = (const float*)d_in[0];
    const float* h0  = (const float*)d_in[1];
    const float* Wa  = (const float*)d_in[2];
    const float* ba  = (const float*)d_in[3];
    const float* Wp1 = (const float*)d_in[4];
    const float* bp1 = (const float*)d_in[5];
    const float* Wp2 = (const float*)d_in[6];
    const float* bp2 = (const float*)d_in[7];
    const float* Wf  = (const float*)d_in[8];
    const float* bf  = (const float*)d_in[9];
    const float* Wg  = (const float*)d_in[10];
    const float* bg  = (const float*)d_in[11];
    const float* Wo  = (const float*)d_in[12];
    const float* bo  = (const float*)d_in[13];
    float* out = (float*)d_out;

    pgjanet_kernel<<<dim3(BB), dim3(64), 0, stream>>>(
        x, h0, Wa, ba, Wp1, bp1, Wp2, bp2, Wf, bf, Wg, bg, Wo, bo, out);
}

// Round 7
// 1685.875 us; speedup vs baseline: 1.3784x; 1.1622x over previous
//
#include <hip/hip_runtime.h>
#include <math.h>

#define BB 256
#define TT 2048
#define HH 64

typedef _Float16 half2v __attribute__((ext_vector_type(2)));
typedef __fp16  fp16v2 __attribute__((ext_vector_type(2)));
union H2I { half2v h; int i; };

__device__ __forceinline__ float tanh_fast(float v) {
    // tanh(x) = 1 - 2/(e^{2x}+1); saturates correctly at +/-inf
    float e = __expf(2.0f * v);
    return 1.0f - 2.0f / (e + 1.0f);
}

__device__ __forceinline__ float fdot2(half2v a, half2v b, float c) {
    return __builtin_amdgcn_fdot2(a, b, c, false);
}

__device__ __forceinline__ half2v pack_pair(float a, float b) {
    fp16v2 r = __builtin_amdgcn_cvt_pkrtz(a, b);
    return __builtin_bit_cast(half2v, r);
}

// force a value to live in a VGPR across the loop (defeat load-rematerialization)
__device__ __forceinline__ void pin_h2(half2v& v) {
    H2I u; u.h = v;
    asm volatile("" : "+v"(u.i));
    v = u.h;
}

// broadcast a packed f16x2 from a wave-uniform lane index to all lanes
__device__ __forceinline__ half2v bcast_pair(half2v v, int lane) {
    H2I u; u.h = v;
    H2I w; w.i = __builtin_amdgcn_readlane(u.i, lane);
    return w.h;
}

// neighbor value within a quad: lane j gets lane j^1 (DPP quad_perm [1,0,3,2])
__device__ __forceinline__ float dpp_neighbor(float v) {
    return __int_as_float(__builtin_amdgcn_mov_dpp(__float_as_int(v), 0xB1, 0xf, 0xf, true));
}

template <int CTRL>
__device__ __forceinline__ float dpp_add_stage(float v) {
    int t = __builtin_amdgcn_update_dpp(0, __float_as_int(v), CTRL, 0xf, 0xf, true);
    return v + __int_as_float(t);
}

// full 64-lane sum, result valid in lane 63; all-VALU (no LDS pipe)
__device__ __forceinline__ float wave_sum_dpp(float v) {
    v = dpp_add_stage<0x111>(v);  // row_shr:1
    v = dpp_add_stage<0x112>(v);  // row_shr:2
    v = dpp_add_stage<0x114>(v);  // row_shr:4
    v = dpp_add_stage<0x118>(v);  // row_shr:8
    v = dpp_add_stage<0x142>(v);  // row_bcast15
    v = dpp_add_stage<0x143>(v);  // row_bcast31 -> lane63 = total
    return v;
}

__global__ __launch_bounds__(256, 1)
void pgjanet_kernel(const float* __restrict__ x,
                    const float* __restrict__ h0,
                    const float* __restrict__ Wa,  const float* __restrict__ ba,
                    const float* __restrict__ Wp1, const float* __restrict__ bp1,
                    const float* __restrict__ Wp2, const float* __restrict__ bp2,
                    const float* __restrict__ Wf,  const float* __restrict__ bf,
                    const float* __restrict__ Wg,  const float* __restrict__ bg,
                    const float* __restrict__ Wo,  const float* __restrict__ bo,
                    float* __restrict__ out)
{
    const int b   = blockIdx.x;
    const int tid = threadIdx.x;
    const int j   = tid & 63;                                   // hidden index
    const int w   = __builtin_amdgcn_readfirstlane(tid >> 6);   // wave 0..3
    const int kb  = w * 16;                                     // k-slice base

    __shared__ float xs[TT * 2];         // 16 KB staged input
    __shared__ float partA[3][HH][4];    // a,p1,p2 partials  [gate][j][wave]
    __shared__ float partC[2][HH][4];    // f,g totals' partials

    // ---- stage x ----
    {
        const float* xp = x + (size_t)b * (TT * 2);
        for (int i = tid; i < TT * 2; i += 256) xs[i] = xp[i];
    }

    // ---- preload this wave's k-slice of each matrix, f16-packed (56 VGPRs) ----
    half2v wa[8], wp1[8], wp2[8], wfh[8], wfu[8], wgh[8], wgu[8];
#pragma unroll
    for (int m = 0; m < 8; ++m) {
        const int k = kb + 2 * m;
        wa[m]  = pack_pair(Wa [j * (HH + 1) + k], Wa [j * (HH + 1) + k + 1]);
        wp1[m] = pack_pair(Wp1[j * (HH + 1) + k], Wp1[j * (HH + 1) + k + 1]);
        wp2[m] = pack_pair(Wp2[j * (HH + 1) + k], Wp2[j * (HH + 1) + k + 1]);
        wfh[m] = pack_pair(Wf [j * (2 * HH) + k], Wf [j * (2 * HH) + k + 1]);
        wfu[m] = pack_pair(Wf [j * (2 * HH) + HH + k], Wf [j * (2 * HH) + HH + k + 1]);
        wgh[m] = pack_pair(Wg [j * (2 * HH) + k], Wg [j * (2 * HH) + k + 1]);
        wgu[m] = pack_pair(Wg [j * (2 * HH) + HH + k], Wg [j * (2 * HH) + HH + k + 1]);
    }
#pragma unroll
    for (int m = 0; m < 8; ++m) {
        pin_h2(wa[m]);  pin_h2(wp1[m]); pin_h2(wp2[m]);
        pin_h2(wfh[m]); pin_h2(wfu[m]); pin_h2(wgh[m]); pin_h2(wgu[m]);
    }

    const float waH  = Wa [j * (HH + 1) + HH];   // extra-column weights (fp32)
    const float wp1H = Wp1[j * (HH + 1) + HH];
    const float wp2H = Wp2[j * (HH + 1) + HH];
    const float ba_r = ba[j], bp1_r = bp1[j], bp2_r = bp2[j];
    const float bf_r = bf[j], bg_r = bg[j];
    const float wo0 = Wo[j], wo1 = Wo[HH + j];
    const float bo0 = bo[0], bo1 = bo[1];

    float h = h0[b * HH + j];
    float* yp = out + (size_t)b * (TT * 2);

    __syncthreads();   // xs ready
    float xi = xs[0], xq = xs[1];

    for (int t = 0; t < TT; ++t) {
        const int tn = (t + 1 < TT) ? (t + 1) : (TT - 1);
        float xi_n = xs[2 * tn];
        float xq_n = xs[2 * tn + 1];

        // pack h pairs; this wave only needs its 8 pairs (k = kb .. kb+15)
        float hnbr = dpp_neighbor(h);
        half2v hp = pack_pair(h, hnbr);
        half2v sh[8];
#pragma unroll
        for (int m = 0; m < 8; ++m) sh[m] = bcast_pair(hp, kb + 2 * m);

        // ---- phase A: 5 independent chains of 8 dot2 over this k-slice ----
        float va = 0.f, v1 = 0.f, v2 = 0.f, vf = 0.f, vg = 0.f;
#pragma unroll
        for (int m = 0; m < 8; ++m) {
            va = fdot2(sh[m], wa[m],  va);
            v1 = fdot2(sh[m], wp1[m], v1);
            v2 = fdot2(sh[m], wp2[m], v2);
            vf = fdot2(sh[m], wfh[m], vf);
            vg = fdot2(sh[m], wgh[m], vg);
        }
        partA[0][j][w] = va;
        partA[1][j][w] = v1;
        partA[2][j][w] = v2;

        // x-derived scalars (replicated, cheap)
        float amp = sqrtf(xi * xi + xq * xq);
        float inv = (amp > 0.f) ? (1.0f / amp) : 0.0f;
        float ct  = (amp > 0.f) ? (xi * inv) : 1.0f;   // cos(atan2(q,i)); atan2(0,0)=0
        float st  = xq * inv;                          // sin(atan2(q,i))

        __syncthreads();   // barrier 1

        const float4 pa = *reinterpret_cast<const float4*>(partA[0][j]);
        const float4 p1v = *reinterpret_cast<const float4*>(partA[1][j]);
        const float4 p2v = *reinterpret_cast<const float4*>(partA[2][j]);
        float pre_a = (pa.x + pa.y) + (pa.z + pa.w) + fmaf(amp, waH,  ba_r);
        float pre_1 = (p1v.x + p1v.y) + (p1v.z + p1v.w) + fmaf(ct, wp1H, bp1_r);
        float pre_2 = (p2v.x + p2v.y) + (p2v.z + p2v.w) + fmaf(st, wp2H, bp2_r);
        float a  = tanh_fast(pre_a);
        float p1 = tanh_fast(pre_1);
        float p2 = tanh_fast(pre_2);
        float u  = (a * (1.f - a)) * (p1 * (1.f - p1)) * (p2 * (1.f - p2));

        // pack + broadcast this wave's u pairs
        float unbr = dpp_neighbor(u);
        half2v up = pack_pair(u, unbr);
        half2v su[8];
#pragma unroll
        for (int m = 0; m < 8; ++m) su[m] = bcast_pair(up, kb + 2 * m);

        // ---- phase C: u-part of f,g; fold in phase-A h-part before writing ----
        float uf = vf, ug = vg;
#pragma unroll
        for (int m = 0; m < 8; ++m) {
            uf = fdot2(su[m], wfu[m], uf);
            ug = fdot2(su[m], wgu[m], ug);
        }
        partC[0][j][w] = uf;
        partC[1][j][w] = ug;

        __syncthreads();   // barrier 2

        const float4 pf = *reinterpret_cast<const float4*>(partC[0][j]);
        const float4 pg = *reinterpret_cast<const float4*>(partC[1][j]);
        float pre_f = (pf.x + pf.y) + (pf.z + pf.w) + bf_r;
        float pre_g = (pg.x + pg.y) + (pg.z + pg.w) + bg_r;
        float f = 1.0f / (1.0f + __expf(-pre_f));
        float g = tanh_fast(pre_g);
        h = fmaf(f, h - g, g);   // f*h + (1-f)*g

        // y_t = h @ Wo.T + bo — rotating wave, all-VALU DPP reduce
        if (w == (t & 3)) {
            float y0 = wave_sum_dpp(h * wo0);
            float y1 = wave_sum_dpp(h * wo1);
            if (j == 63) {
                yp[2 * t]     = y0 + bo0;
                yp[2 * t + 1] = y1 + bo1;
            }
        }

        xi = xi_n; xq = xq_n;
    }
}

extern "C" void kernel_launch(void* const* d_in, const int* in_sizes, int n_in,
                              void* d_out, int out_size, void* d_ws, size_t ws_size,
                              hipStream_t stream) {
    const float* x   = (const float*)d_in[0];
    const float* h0  = (const float*)d_in[1];
    const float* Wa  = (const float*)d_in[2];
    const float* ba  = (const float*)d_in[3];
    const float* Wp1 = (const float*)d_in[4];
    const float* bp1 = (const float*)d_in[5];
    const float* Wp2 = (const float*)d_in[6];
    const float* bp2 = (const float*)d_in[7];
    const float* Wf  = (const float*)d_in[8];
    const float* bf  = (const float*)d_in[9];
    const float* Wg  = (const float*)d_in[10];
    const float* bg  = (const float*)d_in[11];
    const float* Wo  = (const float*)d_in[12];
    const float* bo  = (const float*)d_in[13];
    float* out = (float*)d_out;

    pgjanet_kernel<<<dim3(BB), dim3(256), 0, stream>>>(
        x, h0, Wa, ba, Wp1, bp1, Wp2, bp2, Wf, bf, Wg, bg, Wo, bo, out);
}

// Round 8
// 1634.138 us; speedup vs baseline: 1.4221x; 1.0317x over previous
//
#include <hip/hip_runtime.h>
#include <math.h>

#define BB 256
#define TT 2048
#define HH 64

typedef _Float16 half2v __attribute__((ext_vector_type(2)));
typedef __fp16  fp16v2 __attribute__((ext_vector_type(2)));
union H2I { half2v h; int i; };

__device__ __forceinline__ float tanh_fast(float v) {
    // tanh(x) = 1 - 2/(e^{2x}+1); saturates correctly at +/-inf
    float e = __expf(2.0f * v);
    return 1.0f - 2.0f / (e + 1.0f);
}

__device__ __forceinline__ float fdot2(half2v a, half2v b, float c) {
    return __builtin_amdgcn_fdot2(a, b, c, false);
}

__device__ __forceinline__ half2v pack_pair(float a, float b) {
    fp16v2 r = __builtin_amdgcn_cvt_pkrtz(a, b);
    return __builtin_bit_cast(half2v, r);
}

// force a value to live in a VGPR across the loop (defeat load-rematerialization)
__device__ __forceinline__ void pin_h2(half2v& v) {
    H2I u; u.h = v;
    asm volatile("" : "+v"(u.i));
    v = u.h;
}

// broadcast a packed f16x2 from a wave-uniform lane index to all lanes
__device__ __forceinline__ half2v bcast_pair(half2v v, int lane) {
    H2I u; u.h = v;
    H2I w; w.i = __builtin_amdgcn_readlane(u.i, lane);
    return w.h;
}

// neighbor value within a quad: lane j gets lane j^1 (DPP quad_perm [1,0,3,2])
__device__ __forceinline__ float dpp_neighbor(float v) {
    return __int_as_float(__builtin_amdgcn_mov_dpp(__float_as_int(v), 0xB1, 0xf, 0xf, true));
}

template <int CTRL>
__device__ __forceinline__ float dpp_add_stage(float v) {
    int t = __builtin_amdgcn_update_dpp(0, __float_as_int(v), CTRL, 0xf, 0xf, true);
    return v + __int_as_float(t);
}

// full 64-lane sum, result valid in lane 63; all-VALU (no LDS pipe)
__device__ __forceinline__ float wave_sum_dpp(float v) {
    v = dpp_add_stage<0x111>(v);  // row_shr:1
    v = dpp_add_stage<0x112>(v);  // row_shr:2
    v = dpp_add_stage<0x114>(v);  // row_shr:4
    v = dpp_add_stage<0x118>(v);  // row_shr:8
    v = dpp_add_stage<0x142>(v);  // row_bcast15
    v = dpp_add_stage<0x143>(v);  // row_bcast31 -> lane63 = total
    return v;
}

__global__ __launch_bounds__(256, 1)
void pgjanet_kernel(const float* __restrict__ x,
                    const float* __restrict__ h0,
                    const float* __restrict__ Wa,  const float* __restrict__ ba,
                    const float* __restrict__ Wp1, const float* __restrict__ bp1,
                    const float* __restrict__ Wp2, const float* __restrict__ bp2,
                    const float* __restrict__ Wf,  const float* __restrict__ bf,
                    const float* __restrict__ Wg,  const float* __restrict__ bg,
                    const float* __restrict__ Wo,  const float* __restrict__ bo,
                    float* __restrict__ out)
{
    const int b   = blockIdx.x;
    const int tid = threadIdx.x;
    const int j   = tid & 63;                                   // hidden index
    const int w   = __builtin_amdgcn_readfirstlane(tid >> 6);   // wave 0..3
    const int kb  = w * 16;                                     // k-slice base

    __shared__ float xs[TT * 2];         // 16 KB staged input
    __shared__ float ybuf[TT * 2];       // 16 KB output staging (no global ops in loop)
    __shared__ float partA[3][4][HH];    // a,p1,p2 partials [gate][wave][j] — conflict-free
    __shared__ float partC[2][4][HH];    // f,g partials

    // ---- stage x ----
    {
        const float* xp = x + (size_t)b * (TT * 2);
        for (int i = tid; i < TT * 2; i += 256) xs[i] = xp[i];
    }

    // ---- preload this wave's k-slice of each matrix, f16-packed (56 VGPRs) ----
    half2v wa[8], wp1[8], wp2[8], wfh[8], wfu[8], wgh[8], wgu[8];
#pragma unroll
    for (int m = 0; m < 8; ++m) {
        const int k = kb + 2 * m;
        wa[m]  = pack_pair(Wa [j * (HH + 1) + k], Wa [j * (HH + 1) + k + 1]);
        wp1[m] = pack_pair(Wp1[j * (HH + 1) + k], Wp1[j * (HH + 1) + k + 1]);
        wp2[m] = pack_pair(Wp2[j * (HH + 1) + k], Wp2[j * (HH + 1) + k + 1]);
        wfh[m] = pack_pair(Wf [j * (2 * HH) + k], Wf [j * (2 * HH) + k + 1]);
        wfu[m] = pack_pair(Wf [j * (2 * HH) + HH + k], Wf [j * (2 * HH) + HH + k + 1]);
        wgh[m] = pack_pair(Wg [j * (2 * HH) + k], Wg [j * (2 * HH) + k + 1]);
        wgu[m] = pack_pair(Wg [j * (2 * HH) + HH + k], Wg [j * (2 * HH) + HH + k + 1]);
    }
#pragma unroll
    for (int m = 0; m < 8; ++m) {
        pin_h2(wa[m]);  pin_h2(wp1[m]); pin_h2(wp2[m]);
        pin_h2(wfh[m]); pin_h2(wfu[m]); pin_h2(wgh[m]); pin_h2(wgu[m]);
    }

    const float waH  = Wa [j * (HH + 1) + HH];   // extra-column weights (fp32)
    const float wp1H = Wp1[j * (HH + 1) + HH];
    const float wp2H = Wp2[j * (HH + 1) + HH];
    const float ba_r = ba[j], bp1_r = bp1[j], bp2_r = bp2[j];
    const float bf_r = bf[j], bg_r = bg[j];
    const float wo0 = Wo[j], wo1 = Wo[HH + j];
    const float bo0 = bo[0], bo1 = bo[1];

    float h = h0[b * HH + j];
    float* yp = out + (size_t)b * (TT * 2);

    __syncthreads();   // xs ready
    float xi = xs[0], xq = xs[1];

    for (int t = 0; t < TT; ++t) {
        const int tn = (t + 1 < TT) ? (t + 1) : (TT - 1);
        float xi_n = xs[2 * tn];
        float xq_n = xs[2 * tn + 1];

        // pack h pairs; this wave only needs its 8 pairs (k = kb .. kb+15)
        float hnbr = dpp_neighbor(h);
        half2v hp = pack_pair(h, hnbr);
        half2v sh[8];
#pragma unroll
        for (int m = 0; m < 8; ++m) sh[m] = bcast_pair(hp, kb + 2 * m);

        // ---- phase A: 5 independent chains of 8 dot2 over this k-slice ----
        float va = 0.f, v1 = 0.f, v2 = 0.f, vf = 0.f, vg = 0.f;
#pragma unroll
        for (int m = 0; m < 8; ++m) {
            va = fdot2(sh[m], wa[m],  va);
            v1 = fdot2(sh[m], wp1[m], v1);
            v2 = fdot2(sh[m], wp2[m], v2);
            vf = fdot2(sh[m], wfh[m], vf);
            vg = fdot2(sh[m], wgh[m], vg);
        }
        partA[0][w][j] = va;   // stride-1 in j: conflict-free
        partA[1][w][j] = v1;
        partA[2][w][j] = v2;

        // x-derived scalars (replicated, cheap)
        float amp = sqrtf(xi * xi + xq * xq);
        float inv = (amp > 0.f) ? (1.0f / amp) : 0.0f;
        float ct  = (amp > 0.f) ? (xi * inv) : 1.0f;   // cos(atan2(q,i)); atan2(0,0)=0
        float st  = xq * inv;                          // sin(atan2(q,i))

        __syncthreads();   // barrier 1

        // conflict-free reads: stride-1 in j across lanes (2 lanes/bank = free)
        float pre_a = (partA[0][0][j] + partA[0][1][j]) + (partA[0][2][j] + partA[0][3][j])
                    + fmaf(amp, waH, ba_r);
        float pre_1 = (partA[1][0][j] + partA[1][1][j]) + (partA[1][2][j] + partA[1][3][j])
                    + fmaf(ct, wp1H, bp1_r);
        float pre_2 = (partA[2][0][j] + partA[2][1][j]) + (partA[2][2][j] + partA[2][3][j])
                    + fmaf(st, wp2H, bp2_r);
        float a  = tanh_fast(pre_a);
        float p1 = tanh_fast(pre_1);
        float p2 = tanh_fast(pre_2);
        float u  = (a * (1.f - a)) * (p1 * (1.f - p1)) * (p2 * (1.f - p2));

        // pack + broadcast this wave's u pairs
        float unbr = dpp_neighbor(u);
        half2v up = pack_pair(u, unbr);
        half2v su[8];
#pragma unroll
        for (int m = 0; m < 8; ++m) su[m] = bcast_pair(up, kb + 2 * m);

        // ---- phase C: u-part of f,g; fold in phase-A h-part before writing ----
        float uf = vf, ug = vg;
#pragma unroll
        for (int m = 0; m < 8; ++m) {
            uf = fdot2(su[m], wfu[m], uf);
            ug = fdot2(su[m], wgu[m], ug);
        }
        partC[0][w][j] = uf;
        partC[1][w][j] = ug;

        __syncthreads();   // barrier 2

        float pre_f = (partC[0][0][j] + partC[0][1][j]) + (partC[0][2][j] + partC[0][3][j]) + bf_r;
        float pre_g = (partC[1][0][j] + partC[1][1][j]) + (partC[1][2][j] + partC[1][3][j]) + bg_r;
        float f = 1.0f / (1.0f + __expf(-pre_f));
        float g = tanh_fast(pre_g);
        h = fmaf(f, h - g, g);   // f*h + (1-f)*g

        // y_t = h @ Wo.T + bo — rotating wave, DPP reduce, buffered in LDS
        if (w == (t & 3)) {
            float y0 = wave_sum_dpp(h * wo0);
            float y1 = wave_sum_dpp(h * wo1);
            if (j == 63) {
                ybuf[2 * t]     = y0 + bo0;
                ybuf[2 * t + 1] = y1 + bo1;
            }
        }

        xi = xi_n; xq = xq_n;
    }

    // ---- flush y to global, coalesced float4 ----
    __syncthreads();
    {
        const float4* ys4 = reinterpret_cast<const float4*>(ybuf);
        float4*       yp4 = reinterpret_cast<float4*>(yp);
#pragma unroll
        for (int i = tid; i < TT * 2 / 4; i += 256) yp4[i] = ys4[i];
    }
}

extern "C" void kernel_launch(void* const* d_in, const int* in_sizes, int n_in,
                              void* d_out, int out_size, void* d_ws, size_t ws_size,
                              hipStream_t stream) {
    const float* x   = (const float*)d_in[0];
    const float* h0  = (const float*)d_in[1];
    const float* Wa  = (const float*)d_in[2];
    const float* ba  = (const float*)d_in[3];
    const float* Wp1 = (const float*)d_in[4];
    const float* bp1 = (const float*)d_in[5];
    const float* Wp2 = (const float*)d_in[6];
    const float* bp2 = (const float*)d_in[7];
    const float* Wf  = (const float*)d_in[8];
    const float* bf  = (const float*)d_in[9];
    const float* Wg  = (const float*)d_in[10];
    const float* bg  = (const float*)d_in[11];
    const float* Wo  = (const float*)d_in[12];
    const float* bo  = (const float*)d_in[13];
    float* out = (float*)d_out;

    pgjanet_kernel<<<dim3(BB), dim3(256), 0, stream>>>(
        x, h0, Wa, ba, Wp1, bp1, Wp2, bp2, Wf, bf, Wg, bg, Wo, bo, out);
}

// Round 9
// 1512.450 us; speedup vs baseline: 1.5365x; 1.0805x over previous
//
#include <hip/hip_runtime.h>
#include <math.h>

#define BB 256
#define TT 2048
#define HH 64

typedef _Float16 half2v __attribute__((ext_vector_type(2)));
typedef __fp16  fp16v2 __attribute__((ext_vector_type(2)));
union H2I { half2v h; int i; };

#if __has_builtin(__builtin_amdgcn_rcpf)
__device__ __forceinline__ float fast_rcp(float v) { return __builtin_amdgcn_rcpf(v); }
#else
__device__ __forceinline__ float fast_rcp(float v) { return 1.0f / v; }
#endif
#if __has_builtin(__builtin_amdgcn_rsqf)
__device__ __forceinline__ float fast_rsq(float v) { return __builtin_amdgcn_rsqf(v); }
#else
__device__ __forceinline__ float fast_rsq(float v) { return rsqrtf(v); }
#endif

__device__ __forceinline__ float tanh_fast(float v) {
    // tanh(x) = 1 - 2/(e^{2x}+1); saturates correctly at +/-inf
    float e = __expf(2.0f * v);
    return fmaf(-2.0f, fast_rcp(e + 1.0f), 1.0f);
}

__device__ __forceinline__ float sigmoid_fast(float v) {
    return fast_rcp(1.0f + __expf(-v));
}

__device__ __forceinline__ float fdot2(half2v a, half2v b, float c) {
    return __builtin_amdgcn_fdot2(a, b, c, false);
}

__device__ __forceinline__ half2v pack_pair(float a, float b) {
    fp16v2 r = __builtin_amdgcn_cvt_pkrtz(a, b);
    return __builtin_bit_cast(half2v, r);
}

// force a value to live in a VGPR across the loop (defeat load-rematerialization)
__device__ __forceinline__ void pin_h2(half2v& v) {
    H2I u; u.h = v;
    asm volatile("" : "+v"(u.i));
    v = u.h;
}

// broadcast a packed f16x2 from a wave-uniform lane index to all lanes
__device__ __forceinline__ half2v bcast_pair(half2v v, int lane) {
    H2I u; u.h = v;
    H2I w; w.i = __builtin_amdgcn_readlane(u.i, lane);
    return w.h;
}

// neighbor value within a quad: lane j gets lane j^1 (DPP quad_perm [1,0,3,2])
__device__ __forceinline__ float dpp_neighbor(float v) {
    return __int_as_float(__builtin_amdgcn_mov_dpp(__float_as_int(v), 0xB1, 0xf, 0xf, true));
}

template <int CTRL>
__device__ __forceinline__ float dpp_add_stage(float v) {
    int t = __builtin_amdgcn_update_dpp(0, __float_as_int(v), CTRL, 0xf, 0xf, true);
    return v + __int_as_float(t);
}

// full 64-lane sum, result valid in lane 63; all-VALU (no LDS pipe)
__device__ __forceinline__ float wave_sum_dpp(float v) {
    v = dpp_add_stage<0x111>(v);  // row_shr:1
    v = dpp_add_stage<0x112>(v);  // row_shr:2
    v = dpp_add_stage<0x114>(v);  // row_shr:4
    v = dpp_add_stage<0x118>(v);  // row_shr:8
    v = dpp_add_stage<0x142>(v);  // row_bcast15
    v = dpp_add_stage<0x143>(v);  // row_bcast31 -> lane63 = total
    return v;
}

__global__ __launch_bounds__(256, 1)
void pgjanet_kernel(const float* __restrict__ x,
                    const float* __restrict__ h0,
                    const float* __restrict__ Wa,  const float* __restrict__ ba,
                    const float* __restrict__ Wp1, const float* __restrict__ bp1,
                    const float* __restrict__ Wp2, const float* __restrict__ bp2,
                    const float* __restrict__ Wf,  const float* __restrict__ bf,
                    const float* __restrict__ Wg,  const float* __restrict__ bg,
                    const float* __restrict__ Wo,  const float* __restrict__ bo,
                    float* __restrict__ out)
{
    const int b   = blockIdx.x;
    const int tid = threadIdx.x;
    const int j   = tid & 63;                                   // hidden index
    const int w   = __builtin_amdgcn_readfirstlane(tid >> 6);   // wave 0..3

    __shared__ float xs[TT * 2];        // 16 KB staged input
    __shared__ float ybuf[TT * 2];      // 16 KB output staging
    __shared__ float exch[2][5][HH];    // double-buffered: a,p1,p2,f_h,g_h

    // ---- stage x ----
    {
        const float* xp = x + (size_t)b * (TT * 2);
        for (int i = tid; i < TT * 2; i += 256) xs[i] = xp[i];
    }

    // ---- per-wave weight assignment ----
    // wave0: a-gate, wave1: p1-gate, wave2: p2-gate, wave3: f_h + g_h
    const float* gsrc  = (w == 0) ? Wa : (w == 1) ? Wp1 : (w == 2) ? Wp2 : Wf;
    const int    gld   = (w < 3) ? (HH + 1) : (2 * HH);
    const float* g2src = (w == 3) ? Wg : gsrc;
    const int    g2ld  = (w == 3) ? (2 * HH) : gld;

    half2v wgate[32], wgate2[32], wfuv[32], wguv[32];
#pragma unroll
    for (int m = 0; m < 32; ++m) {
        wgate[m]  = pack_pair(gsrc [j * gld  + 2 * m], gsrc [j * gld  + 2 * m + 1]);
        wgate2[m] = pack_pair(g2src[j * g2ld + 2 * m], g2src[j * g2ld + 2 * m + 1]);
        wfuv[m]   = pack_pair(Wf[j * (2 * HH) + HH + 2 * m], Wf[j * (2 * HH) + HH + 2 * m + 1]);
        wguv[m]   = pack_pair(Wg[j * (2 * HH) + HH + 2 * m], Wg[j * (2 * HH) + HH + 2 * m + 1]);
    }
#pragma unroll
    for (int m = 0; m < 32; ++m) {
        pin_h2(wgate[m]); pin_h2(wgate2[m]); pin_h2(wfuv[m]); pin_h2(wguv[m]);
    }

    const float xw   = (w == 0) ? Wa [j * (HH + 1) + HH]
                     : (w == 1) ? Wp1[j * (HH + 1) + HH]
                     : (w == 2) ? Wp2[j * (HH + 1) + HH] : 0.f;
    const float bsel = (w == 0) ? ba[j] : (w == 1) ? bp1[j] : (w == 2) ? bp2[j] : 0.f;
    const float bf_r = bf[j], bg_r = bg[j];
    const float wo0 = Wo[j], wo1 = Wo[HH + j];
    const float bo0 = bo[0], bo1 = bo[1];

    float h = h0[b * HH + j];
    float* yp = out + (size_t)b * (TT * 2);

    __syncthreads();   // xs ready

    // x-scalar pipeline (amp/cos/sin via one rsq), selected per wave role
    float xsel;
    {
        float xi = xs[0], xq = xs[1];
        float r2 = xi * xi + xq * xq;
        float rsq = fast_rsq(r2);
        bool ok = r2 > 0.f;
        float amp = ok ? r2 * rsq : 0.f;
        float ct  = ok ? xi * rsq : 1.f;   // cos(atan2(q,i)); atan2(0,0)=0
        float st  = ok ? xq * rsq : 0.f;
        xsel = (w == 0) ? amp : (w == 1) ? ct : st;
    }

    for (int t = 0; t < TT; ++t) {
        float (*ex)[HH] = exch[t & 1];

        // next step's x scalars (off the critical path)
        const int tn = (t + 1 < TT) ? (t + 1) : (TT - 1);
        float xi_n = xs[2 * tn], xq_n = xs[2 * tn + 1];
        float xsel_n;
        {
            float r2 = xi_n * xi_n + xq_n * xq_n;
            float rsq = fast_rsq(r2);
            bool ok = r2 > 0.f;
            float amp = ok ? r2 * rsq : 0.f;
            float ct  = ok ? xi_n * rsq : 1.f;
            float st  = ok ? xq_n * rsq : 0.f;
            xsel_n = (w == 0) ? amp : (w == 1) ? ct : st;
        }

        // broadcast all 32 h pairs
        float hnbr = dpp_neighbor(h);
        half2v hp = pack_pair(h, hnbr);
        half2v sh[32];
#pragma unroll
        for (int m = 0; m < 32; ++m) sh[m] = bcast_pair(hp, 2 * m);

        // ---- phase A (gate-split): 32 dot2, 4 accumulators ----
        float a0 = 0.f, a1 = 0.f, a2 = 0.f, a3 = 0.f;
#pragma unroll
        for (int m = 0; m < 8; ++m) {
            a0 = fdot2(sh[m],      wgate[m],      a0);
            a1 = fdot2(sh[m + 8],  wgate[m + 8],  a1);
            a2 = fdot2(sh[m + 16], wgate[m + 16], a2);
            a3 = fdot2(sh[m + 24], wgate[m + 24], a3);
        }
        float pre = (a0 + a1) + (a2 + a3);

        if (w == 3) {
            // g_h as well (second 32 dot2); no tanh on this wave
            float b0 = 0.f, b1 = 0.f, b2 = 0.f, b3 = 0.f;
#pragma unroll
            for (int m = 0; m < 8; ++m) {
                b0 = fdot2(sh[m],      wgate2[m],      b0);
                b1 = fdot2(sh[m + 8],  wgate2[m + 8],  b1);
                b2 = fdot2(sh[m + 16], wgate2[m + 16], b2);
                b3 = fdot2(sh[m + 24], wgate2[m + 24], b3);
            }
            ex[3][j] = pre + bf_r;                      // f_h + bf
            ex[4][j] = ((b0 + b1) + (b2 + b3)) + bg_r;  // g_h + bg
        } else {
            // tanh applied pre-barrier: off the post-barrier critical path
            ex[w][j] = tanh_fast(pre + fmaf(xsel, xw, bsel));
        }

        __syncthreads();   // single barrier per step

        float av  = ex[0][j];
        float pv1 = ex[1][j];
        float pv2 = ex[2][j];
        float fh  = ex[3][j];
        float gh  = ex[4][j];
        float u = (av * (1.f - av)) * (pv1 * (1.f - pv1)) * (pv2 * (1.f - pv2));

        // broadcast all 32 u pairs
        float unbr = dpp_neighbor(u);
        half2v upk = pack_pair(u, unbr);
        half2v su[32];
#pragma unroll
        for (int m = 0; m < 32; ++m) su[m] = bcast_pair(upk, 2 * m);

        // ---- phase C replicated: f,g u-parts (64 dot2, 8 chains) ----
        float f0 = 0.f, f1 = 0.f, f2 = 0.f, f3 = 0.f;
        float g0 = 0.f, g1 = 0.f, g2 = 0.f, g3 = 0.f;
#pragma unroll
        for (int m = 0; m < 8; ++m) {
            f0 = fdot2(su[m],      wfuv[m],      f0);
            f1 = fdot2(su[m + 8],  wfuv[m + 8],  f1);
            f2 = fdot2(su[m + 16], wfuv[m + 16], f2);
            f3 = fdot2(su[m + 24], wfuv[m + 24], f3);
            g0 = fdot2(su[m],      wguv[m],      g0);
            g1 = fdot2(su[m + 8],  wguv[m + 8],  g1);
            g2 = fdot2(su[m + 16], wguv[m + 16], g2);
            g3 = fdot2(su[m + 24], wguv[m + 24], g3);
        }
        float f = sigmoid_fast(fh + (f0 + f1) + (f2 + f3));
        float g = tanh_fast(gh + (g0 + g1) + (g2 + g3));
        h = fmaf(f, h - g, g);   // f*h + (1-f)*g  (identical in all waves)

        // y_t = h @ Wo.T + bo — rotating wave, DPP reduce, buffered in LDS
        if (w == (t & 3)) {
            float y0 = wave_sum_dpp(h * wo0);
            float y1 = wave_sum_dpp(h * wo1);
            if (j == 63) {
                ybuf[2 * t]     = y0 + bo0;
                ybuf[2 * t + 1] = y1 + bo1;
            }
        }

        xsel = xsel_n;
    }

    // ---- flush y to global, coalesced float4 ----
    __syncthreads();
    {
        const float4* ys4 = reinterpret_cast<const float4*>(ybuf);
        float4*       yp4 = reinterpret_cast<float4*>(yp);
        for (int i = tid; i < TT * 2 / 4; i += 256) yp4[i] = ys4[i];
    }
}

extern "C" void kernel_launch(void* const* d_in, const int* in_sizes, int n_in,
                              void* d_out, int out_size, void* d_ws, size_t ws_size,
                              hipStream_t stream) {
    const float* x   = (const float*)d_in[0];
    const float* h0  = (const float*)d_in[1];
    const float* Wa  = (const float*)d_in[2];
    const float* ba  = (const float*)d_in[3];
    const float* Wp1 = (const float*)d_in[4];
    const float* bp1 = (const float*)d_in[5];
    const float* Wp2 = (const float*)d_in[6];
    const float* bp2 = (const float*)d_in[7];
    const float* Wf  = (const float*)d_in[8];
    const float* bf  = (const float*)d_in[9];
    const float* Wg  = (const float*)d_in[10];
    const float* bg  = (const float*)d_in[11];
    const float* Wo  = (const float*)d_in[12];
    const float* bo  = (const float*)d_in[13];
    float* out = (float*)d_out;

    pgjanet_kernel<<<dim3(BB), dim3(256), 0, stream>>>(
        x, h0, Wa, ba, Wp1, bp1, Wp2, bp2, Wf, bf, Wg, bg, Wo, bo, out);
}